// Round 2
// baseline (4268.164 us; speedup 1.0000x reference)
//
#include <hip/hip_runtime.h>
#include <hip/hip_bf16.h>

#define HDIM 32
#define NL 8
#define NBATCH 256
#define TLEN 4096

typedef __attribute__((ext_vector_type(8))) unsigned short u16x8;

__device__ __forceinline__ float bf2f(unsigned short u) {
  union { unsigned int i; float f; } v;
  v.i = ((unsigned int)u) << 16;
  return v.f;
}

__device__ __forceinline__ float fast_tanh(float x) {
  float e2 = __expf(2.0f * x);
#if __has_builtin(__builtin_amdgcn_rcpf)
  float r = __builtin_amdgcn_rcpf(e2 + 1.0f);
#else
  float r = 1.0f / (e2 + 1.0f);
#endif
  return 1.0f - 2.0f * r;
}

// dtype-generic loads: BF16 => packed __hip_bfloat16, else fp32
template <bool BF16>
__device__ __forceinline__ float ld1(const void* p, int off) {
  return BF16 ? bf2f(((const unsigned short*)p)[off]) : ((const float*)p)[off];
}

template <bool BF16>
__device__ __forceinline__ void ld32(const void* p, int elem_off, float* dst) {
  if (BF16) {
    const u16x8* wp = (const u16x8*)((const unsigned short*)p + elem_off);
#pragma unroll
    for (int m = 0; m < 4; ++m) {
      u16x8 v = wp[m];
#pragma unroll
      for (int e = 0; e < 8; ++e) dst[m * 8 + e] = bf2f(v[e]);
    }
  } else {
    const float4* wp = (const float4*)((const float*)p + elem_off);
#pragma unroll
    for (int m = 0; m < 8; ++m) {
      float4 v = wp[m];
      dst[m * 4 + 0] = v.x; dst[m * 4 + 1] = v.y;
      dst[m * 4 + 2] = v.z; dst[m * 4 + 3] = v.w;
    }
  }
}

// One 8-layer RNN stack, wavefront-pipelined across layers.
// Thread (l = tid>>5, j = tid&31) owns output element j of layer l.
// ybuf[buf][slot][j]: slot 0 = input vector ([x_t,0,...,0]); slot l+1 = layer l output.
// Wave 3 (layers 6,7) additionally computes the 32-wide fc dot on the
// previous step's top-layer output (16 MACs per half + shfl_xor combine).
template <int PHASE, bool BF16>
__device__ __forceinline__ void run_stack(
    int b, int tid, int l, int j,
    const void* __restrict__ Wih0,
    const void* __restrict__ Wih,
    const void* __restrict__ Whh,
    const void* __restrict__ bih,
    const void* __restrict__ bhh,
    const void* __restrict__ fcW,
    const void* __restrict__ fcb,
    const float* __restrict__ seq,      // per-t scalar input stream (x or mid)
    float* __restrict__ mid,            // PHASE 0: write fc result here (LDS)
    void* __restrict__ out,             // PHASE 1: write fc result here (global y)
    float (&ybuf)[2][NL + 1][HDIM],
    float& hreg)
{
  // ---- per-thread weights in registers (widened to fp32) ----
  float wih[HDIM], whh[HDIM];
  ld32<BF16>(Whh, (l * HDIM + j) * HDIM, whh);
  if (l == 0) {
#pragma unroll
    for (int k = 0; k < HDIM; ++k) wih[k] = 0.0f;
    wih[0] = ld1<BF16>(Wih0, j);
  } else {
    ld32<BF16>(Wih, ((l - 1) * HDIM + j) * HDIM, wih);
  }
  const float bias = ld1<BF16>(bih, l * HDIM + j) + ld1<BF16>(bhh, l * HDIM + j);

  float fcd[16];
  const int k0 = (l & 1) << 4;
#pragma unroll
  for (int k = 0; k < 16; ++k) fcd[k] = ld1<BF16>(fcW, k0 + k);
  const float fcbias = ld1<BF16>(fcb, 0);

  // ---- init LDS state: both buffers hold h0; input slot zeroed ----
  ybuf[0][l + 1][j] = hreg;
  ybuf[1][l + 1][j] = hreg;
  if (tid < HDIM) { ybuf[0][0][tid] = 0.0f; ybuf[1][0][tid] = 0.0f; }
  __syncthreads();                      // also orders seq[] fill before read
  if (tid == 0) ybuf[0][0][0] = seq[0];
  __syncthreads();

  // ---- wavefront pipeline: step s, layer l handles t = s - l ----
  for (int s = 0; s < TLEN + NL; ++s) {
    const int pb = s & 1;
    const int cb = pb ^ 1;
    const int t = s - l;
    const bool act = ((unsigned)t < (unsigned)TLEN);
    float hnew = 0.0f;
    if (act) {
      const float4* iv = (const float4*)ybuf[pb][l];       // input vec
      const float4* hv = (const float4*)ybuf[pb][l + 1];   // own prev h
      float a0 = bias, a1 = 0.0f, a2 = 0.0f, a3 = 0.0f;
#pragma unroll
      for (int q = 0; q < 8; ++q) {
        const float4 A = iv[q];
        const float4 B = hv[q];
        a0 = fmaf(wih[4 * q + 0], A.x, a0);
        a1 = fmaf(wih[4 * q + 1], A.y, a1);
        a2 = fmaf(wih[4 * q + 2], A.z, a2);
        a3 = fmaf(wih[4 * q + 3], A.w, a3);
        a0 = fmaf(whh[4 * q + 0], B.x, a0);
        a1 = fmaf(whh[4 * q + 1], B.y, a1);
        a2 = fmaf(whh[4 * q + 2], B.z, a2);
        a3 = fmaf(whh[4 * q + 3], B.w, a3);
      }
      hnew = fast_tanh((a0 + a1) + (a2 + a3));
      hreg = hnew;                       // last active step leaves t=T-1 state
    }
    // fc dot over previous step's top-layer output (time tm = s - 8)
    if ((tid >> 6) == 3) {               // wave-uniform: layers 6,7
      const int tm = s - NL;
      if (tm >= 0) {
        const float* ytop = ybuf[pb][NL];
        float p0 = 0.0f, p1 = 0.0f;
#pragma unroll
        for (int k = 0; k < 16; k += 2) {
          p0 = fmaf(fcd[k],     ytop[k0 + k],     p0);
          p1 = fmaf(fcd[k + 1], ytop[k0 + k + 1], p1);
        }
        float p = p0 + p1;
        p += __shfl_xor(p, 32, 64);      // combine the two half-dots
        if ((tid & 63) == 0) {
          float val = p + fcbias;
          if (PHASE == 0) {
            mid[tm] = val;
          } else {
            if (BF16)
              ((__hip_bfloat16*)out)[(size_t)b * TLEN + tm] = __float2bfloat16(val);
            else
              ((float*)out)[(size_t)b * TLEN + tm] = val;
          }
        }
      }
    }
    if (act) ybuf[cb][l + 1][j] = hnew;
    if (tid == 0) ybuf[cb][0][0] = (s + 1 < TLEN) ? seq[s + 1] : 0.0f;
    __syncthreads();                     // one barrier/step (double-buffered)
  }
}

// Dtype probe: if x holds packed bf16, the LOW 16 bits of each dword are a
// bf16 of N(0,1) -> exponent field concentrated in [112,132]. If x is fp32,
// the low 16 bits are random mantissa -> exponent field ~uniform (8% hit).
__global__ void detect_dtype_kernel(const unsigned int* __restrict__ xu,
                                    int* __restrict__ flag) {
  const int tid = threadIdx.x;
  unsigned int u = xu[tid];
  unsigned int lo = u & 0xFFFFu;
  int e = (int)((lo >> 7) & 0xFFu);
  int vote = (e >= 112 && e <= 132) ? 1 : 0;
  int cnt = __syncthreads_count(vote);
  if (tid == 0) *flag = (cnt > 128) ? 1 : 0;
}

template <bool BF16>
__global__ __launch_bounds__(256) void radar_rnn_kernel(
    const int* __restrict__ flag,
    const void* __restrict__ x,
    const void* __restrict__ h0,
    const void* __restrict__ W1ih0, const void* __restrict__ W1ih,
    const void* __restrict__ W1hh,  const void* __restrict__ b1ih,
    const void* __restrict__ b1hh,  const void* __restrict__ fc1W,
    const void* __restrict__ fc1b,
    const void* __restrict__ W2ih0, const void* __restrict__ W2ih,
    const void* __restrict__ W2hh,  const void* __restrict__ b2ih,
    const void* __restrict__ b2hh,  const void* __restrict__ outW,
    const void* __restrict__ outb,
    void* __restrict__ out)
{
  if (*flag != (BF16 ? 1 : 0)) return;   // wrong-dtype instantiation: exit

  __shared__ __align__(16) float seq[TLEN];                 // x scalars (fp32)
  __shared__ __align__(16) float midbuf[TLEN];              // inter-stack scalars
  __shared__ __align__(16) float ybuf[2][NL + 1][HDIM];

  const int tid = threadIdx.x;
  const int b = blockIdx.x;
  const int l = tid >> 5;
  const int j = tid & 31;

  // stage x[b, :] into LDS as fp32 (vectorized 16B loads)
  if (BF16) {
    const u16x8* xv = (const u16x8*)((const unsigned short*)x + (size_t)b * TLEN);
    for (int i = tid; i < TLEN / 8; i += 256) {
      u16x8 v = xv[i];
#pragma unroll
      for (int e = 0; e < 8; ++e) seq[i * 8 + e] = bf2f(v[e]);
    }
  } else {
    const float4* xv = (const float4*)((const float*)x + (size_t)b * TLEN);
    for (int i = tid; i < TLEN / 4; i += 256) {
      float4 v = xv[i];
      seq[i * 4 + 0] = v.x; seq[i * 4 + 1] = v.y;
      seq[i * 4 + 2] = v.z; seq[i * 4 + 3] = v.w;
    }
  }

  float hreg = ld1<BF16>(h0, (l * NBATCH + b) * HDIM + j);

  // stack 1: x -> r1, fc1 dot -> midbuf; hreg becomes h1 (stack-2 init state)
  run_stack<0, BF16>(b, tid, l, j, W1ih0, W1ih, W1hh, b1ih, b1hh, fc1W, fc1b,
                     seq, midbuf, out, ybuf, hreg);
  // stack 2: midbuf -> r2, out dot -> y; hreg becomes h2
  run_stack<1, BF16>(b, tid, l, j, W2ih0, W2ih, W2hh, b2ih, b2hh, outW, outb,
                     midbuf, midbuf, out, ybuf, hreg);

  // final hidden states h2: [L, B, H]
  const size_t hidx = (size_t)NBATCH * TLEN + (size_t)(l * NBATCH + b) * HDIM + j;
  if (BF16)
    ((__hip_bfloat16*)out)[hidx] = __float2bfloat16(hreg);
  else
    ((float*)out)[hidx] = hreg;
}

extern "C" void kernel_launch(void* const* d_in, const int* in_sizes, int n_in,
                              void* d_out, int out_size, void* d_ws, size_t ws_size,
                              hipStream_t stream) {
  int* flag = (int*)d_ws;
  detect_dtype_kernel<<<dim3(1), dim3(256), 0, stream>>>(
      (const unsigned int*)d_in[0], flag);

  radar_rnn_kernel<true><<<dim3(NBATCH), dim3(256), 0, stream>>>(
      flag, d_in[0], d_in[1], d_in[2], d_in[3], d_in[4], d_in[5], d_in[6],
      d_in[7], d_in[8], d_in[9], d_in[10], d_in[11], d_in[12], d_in[13],
      d_in[14], d_in[15], d_out);
  radar_rnn_kernel<false><<<dim3(NBATCH), dim3(256), 0, stream>>>(
      flag, d_in[0], d_in[1], d_in[2], d_in[3], d_in[4], d_in[5], d_in[6],
      d_in[7], d_in[8], d_in[9], d_in[10], d_in[11], d_in[12], d_in[13],
      d_in[14], d_in[15], d_out);
}

// Round 3
// 2996.121 us; speedup vs baseline: 1.4246x; 1.4246x over previous
//
#include <hip/hip_runtime.h>
#include <hip/hip_bf16.h>

#define HDIM 32
#define NL 8
#define NBATCH 256
#define TLEN 4096
#define NTHR 512

typedef __attribute__((ext_vector_type(8))) unsigned short u16x8;

__device__ __forceinline__ float bf2f(unsigned short u) {
  union { unsigned int i; float f; } v;
  v.i = ((unsigned int)u) << 16;
  return v.f;
}

__device__ __forceinline__ float fast_tanh(float x) {
  // tanh(x) = 1 - 2/(exp(2x)+1); exp(2x) = 2^(x * 2/ln2)
  float e2 = exp2f(x * 2.8853900817779268f);
#if __has_builtin(__builtin_amdgcn_rcpf)
  float r = __builtin_amdgcn_rcpf(e2 + 1.0f);
#else
  float r = 1.0f / (e2 + 1.0f);
#endif
  return 1.0f - 2.0f * r;
}

template <bool BF16>
__device__ __forceinline__ float ld1(const void* p, int off) {
  return BF16 ? bf2f(((const unsigned short*)p)[off]) : ((const float*)p)[off];
}

// load 16 contiguous elements, widened to fp32
template <bool BF16>
__device__ __forceinline__ void ld16(const void* p, int elem_off, float* dst) {
  if (BF16) {
    const u16x8* wp = (const u16x8*)((const unsigned short*)p + elem_off);
#pragma unroll
    for (int m = 0; m < 2; ++m) {
      u16x8 v = wp[m];
#pragma unroll
      for (int e = 0; e < 8; ++e) dst[m * 8 + e] = bf2f(v[e]);
    }
  } else {
    const float4* wp = (const float4*)((const float*)p + elem_off);
#pragma unroll
    for (int m = 0; m < 4; ++m) {
      float4 v = wp[m];
      dst[m * 4 + 0] = v.x; dst[m * 4 + 1] = v.y;
      dst[m * 4 + 2] = v.z; dst[m * 4 + 3] = v.w;
    }
  }
}

// 8-layer RNN stack, wavefront-pipelined: wave = layer l (= tid>>6).
// Within a wave, lanes (j, j+32) split row j's 64-MAC dot (16 ih + 16 hh
// each), combined with shfl_xor(32). One __syncthreads per step
// (double-buffered ybuf). Wave 0 (scalar-input layer -> lightest) also
// computes the fc dot on the previous step's top-layer output.
// NO global memory ops inside the loop: fc results -> mid[] (LDS).
template <bool BF16>
__device__ __forceinline__ void run_stack(
    int tid, int l, int j, int kh,
    const void* __restrict__ Wih0,
    const void* __restrict__ Wih,
    const void* __restrict__ Whh,
    const void* __restrict__ bih,
    const void* __restrict__ bhh,
    const void* __restrict__ fcW,
    const void* __restrict__ fcb,
    const float* __restrict__ seq,   // input scalar stream (LDS)
    float* __restrict__ mid,         // fc output stream (LDS)
    float (&ybuf)[2][NL + 1][HDIM],
    float& hreg)
{
  const int koff = kh << 4;
  float whh[16], wih[16], fcd[16];
  float w0 = 0.0f;
  ld16<BF16>(Whh, (l * HDIM + j) * HDIM + koff, whh);
  if (l == 0) {
#pragma unroll
    for (int i = 0; i < 16; ++i) wih[i] = 0.0f;
    w0 = kh ? 0.0f : ld1<BF16>(Wih0, j);
#pragma unroll
    for (int i = 0; i < 16; ++i) fcd[i] = ld1<BF16>(fcW, koff + i);
  } else {
    ld16<BF16>(Wih, ((l - 1) * HDIM + j) * HDIM + koff, wih);
#pragma unroll
    for (int i = 0; i < 16; ++i) fcd[i] = 0.0f;
  }
  const float bias =
      kh ? 0.0f : (ld1<BF16>(bih, l * HDIM + j) + ld1<BF16>(bhh, l * HDIM + j));
  const float fcbias = ld1<BF16>(fcb, 0);

  // init: both buffers hold h0 (read by layer l at its first active steps)
  if (!kh) { ybuf[0][l + 1][j] = hreg; ybuf[1][l + 1][j] = hreg; }
  __syncthreads();

#pragma unroll 2
  for (int s = 0; s < TLEN + NL; ++s) {
    const int pb = s & 1;
    const int cb = pb ^ 1;
    const int t = s - l;
    const bool act = ((unsigned)t < (unsigned)TLEN);
    float p;
    if (l == 0) {
      const float4* hv = (const float4*)&ybuf[pb][1][koff];
      float a0 = bias, a1 = 0.0f;
#pragma unroll
      for (int q = 0; q < 4; ++q) {
        const float4 B = hv[q];
        a0 = fmaf(whh[4 * q + 0], B.x, a0);
        a1 = fmaf(whh[4 * q + 1], B.y, a1);
        a0 = fmaf(whh[4 * q + 2], B.z, a0);
        a1 = fmaf(whh[4 * q + 3], B.w, a1);
      }
      const float xt = act ? seq[t] : 0.0f;   // t == s for layer 0
      a0 = fmaf(w0, xt, a0);
      p = a0 + a1;
      // fc dot over previous step's top-layer output (time tm = s - 8)
      const int tm = s - NL;
      if (tm >= 0) {
        const float4* yv = (const float4*)&ybuf[pb][NL][koff];
        float f0 = 0.0f, f1 = 0.0f;
#pragma unroll
        for (int q = 0; q < 4; ++q) {
          const float4 Y = yv[q];
          f0 = fmaf(fcd[4 * q + 0], Y.x, f0);
          f1 = fmaf(fcd[4 * q + 1], Y.y, f1);
          f0 = fmaf(fcd[4 * q + 2], Y.z, f0);
          f1 = fmaf(fcd[4 * q + 3], Y.w, f1);
        }
        float f = f0 + f1;
        f += __shfl_xor(f, 32, 64);           // combine k-halves
        if (tid == 0) mid[tm] = f + fcbias;
      }
    } else {
      const float4* iv = (const float4*)&ybuf[pb][l][koff];
      const float4* hv = (const float4*)&ybuf[pb][l + 1][koff];
      float a0 = bias, a1 = 0.0f, a2 = 0.0f, a3 = 0.0f;
#pragma unroll
      for (int q = 0; q < 4; ++q) {
        const float4 A = iv[q];
        const float4 B = hv[q];
        a0 = fmaf(wih[4 * q + 0], A.x, a0);
        a1 = fmaf(wih[4 * q + 1], A.y, a1);
        a2 = fmaf(wih[4 * q + 2], A.z, a2);
        a3 = fmaf(wih[4 * q + 3], A.w, a3);
        a0 = fmaf(whh[4 * q + 0], B.x, a0);
        a1 = fmaf(whh[4 * q + 1], B.y, a1);
        a2 = fmaf(whh[4 * q + 2], B.z, a2);
        a3 = fmaf(whh[4 * q + 3], B.w, a3);
      }
      p = (a0 + a1) + (a2 + a3);
    }
    p += __shfl_xor(p, 32, 64);               // combine k-halves
    const float h = fast_tanh(p);
    if (act) {
      hreg = h;
      if (!kh) ybuf[cb][l + 1][j] = h;
    }
    __syncthreads();                          // one barrier per step
  }
}

// Dtype probe: bf16-packed N(0,1) concentrates the low-half exponent field
// in [112,132]; fp32 low bits are ~uniform mantissa (~8% hit rate).
__global__ void detect_dtype_kernel(const unsigned int* __restrict__ xu,
                                    int* __restrict__ flag) {
  const int tid = threadIdx.x;
  unsigned int lo = xu[tid] & 0xFFFFu;
  int e = (int)((lo >> 7) & 0xFFu);
  int cnt = __syncthreads_count((e >= 112 && e <= 132) ? 1 : 0);
  if (tid == 0) *flag = (cnt > 128) ? 1 : 0;
}

template <bool BF16>
__global__ __launch_bounds__(NTHR) void radar_rnn_kernel(
    const int* __restrict__ flag,
    const void* __restrict__ x,
    const void* __restrict__ h0,
    const void* __restrict__ W1ih0, const void* __restrict__ W1ih,
    const void* __restrict__ W1hh,  const void* __restrict__ b1ih,
    const void* __restrict__ b1hh,  const void* __restrict__ fc1W,
    const void* __restrict__ fc1b,
    const void* __restrict__ W2ih0, const void* __restrict__ W2ih,
    const void* __restrict__ W2hh,  const void* __restrict__ b2ih,
    const void* __restrict__ b2hh,  const void* __restrict__ outW,
    const void* __restrict__ outb,
    void* __restrict__ out)
{
  if (*flag != (BF16 ? 1 : 0)) return;

  __shared__ __align__(16) float seq[TLEN];      // stack-1 input scalars
  __shared__ __align__(16) float midbuf[TLEN];   // fc1 out = stack-2 in = y
  __shared__ __align__(16) float ybuf[2][NL + 1][HDIM];

  const int tid = threadIdx.x;
  const int b = blockIdx.x;
  const int l = tid >> 6;          // wave = layer
  const int lane = tid & 63;
  const int j = lane & 31;         // output row
  const int kh = lane >> 5;        // k-half (split-K 2)

  // stage x[b,:] into LDS as fp32
  if (BF16) {
    const u16x8* xv = (const u16x8*)((const unsigned short*)x + (size_t)b * TLEN);
    for (int i = tid; i < TLEN / 8; i += NTHR) {
      u16x8 v = xv[i];
#pragma unroll
      for (int e = 0; e < 8; ++e) seq[i * 8 + e] = bf2f(v[e]);
    }
  } else {
    const float4* xv = (const float4*)((const float*)x + (size_t)b * TLEN);
    for (int i = tid; i < TLEN / 4; i += NTHR) {
      float4 v = xv[i];
      seq[i * 4 + 0] = v.x; seq[i * 4 + 1] = v.y;
      seq[i * 4 + 2] = v.z; seq[i * 4 + 3] = v.w;
    }
  }

  float hreg = ld1<BF16>(h0, (l * NBATCH + b) * HDIM + j);

  // stack 1: seq -> fc1 results in midbuf; hreg becomes h1
  run_stack<BF16>(tid, l, j, kh, W1ih0, W1ih, W1hh, b1ih, b1hh, fc1W, fc1b,
                  seq, midbuf, ybuf, hreg);
  // stack 2: midbuf as input; out-fc results overwrite consumed midbuf slots
  run_stack<BF16>(tid, l, j, kh, W2ih0, W2ih, W2hh, b2ih, b2hh, outW, outb,
                  midbuf, midbuf, ybuf, hreg);

  __syncthreads();
  // flush y (midbuf) to global, coalesced
  if (BF16) {
    __hip_bfloat16* o = (__hip_bfloat16*)out + (size_t)b * TLEN;
    for (int i = tid; i < TLEN; i += NTHR) o[i] = __float2bfloat16(midbuf[i]);
  } else {
    float* o = (float*)out + (size_t)b * TLEN;
    for (int i = tid; i < TLEN; i += NTHR) o[i] = midbuf[i];
  }
  // final hidden states h2: [L, B, H]
  if (!kh) {
    const size_t hidx =
        (size_t)NBATCH * TLEN + (size_t)(l * NBATCH + b) * HDIM + j;
    if (BF16)
      ((__hip_bfloat16*)out)[hidx] = __float2bfloat16(hreg);
    else
      ((float*)out)[hidx] = hreg;
  }
}

extern "C" void kernel_launch(void* const* d_in, const int* in_sizes, int n_in,
                              void* d_out, int out_size, void* d_ws, size_t ws_size,
                              hipStream_t stream) {
  int* flag = (int*)d_ws;
  detect_dtype_kernel<<<dim3(1), dim3(256), 0, stream>>>(
      (const unsigned int*)d_in[0], flag);

  radar_rnn_kernel<true><<<dim3(NBATCH), dim3(NTHR), 0, stream>>>(
      flag, d_in[0], d_in[1], d_in[2], d_in[3], d_in[4], d_in[5], d_in[6],
      d_in[7], d_in[8], d_in[9], d_in[10], d_in[11], d_in[12], d_in[13],
      d_in[14], d_in[15], d_out);
  radar_rnn_kernel<false><<<dim3(NBATCH), dim3(NTHR), 0, stream>>>(
      flag, d_in[0], d_in[1], d_in[2], d_in[3], d_in[4], d_in[5], d_in[6],
      d_in[7], d_in[8], d_in[9], d_in[10], d_in[11], d_in[12], d_in[13],
      d_in[14], d_in[15], d_out);
}

// Round 5
// 2339.451 us; speedup vs baseline: 1.8244x; 1.2807x over previous
//
#include <hip/hip_runtime.h>
#include <hip/hip_bf16.h>

#define HDIM 32
#define NL 8
#define NBATCH 256
#define TLEN 4096
#define NTHR 512
#define KSUP 4
#define NSUP (TLEN / KSUP)   // 1024 active supersteps per wave
#define NST (NSUP + NL)      // 1032 supersteps total (fill/drain)

typedef __attribute__((ext_vector_type(8))) unsigned short u16x8;

__device__ __forceinline__ float bf2f(unsigned short u) {
  union { unsigned int i; float f; } v;
  v.i = ((unsigned int)u) << 16;
  return v.f;
}

__device__ __forceinline__ float fast_tanh(float x) {
  // tanh(x) = 1 - 2/(exp(2x)+1); exp(2x) = 2^(x * 2/ln2)
  float e2 = exp2f(x * 2.8853900817779268f);
#if __has_builtin(__builtin_amdgcn_rcpf)
  float r = __builtin_amdgcn_rcpf(e2 + 1.0f);
#else
  float r = 1.0f / (e2 + 1.0f);
#endif
  return 1.0f - 2.0f * r;
}

template <bool BF16>
__device__ __forceinline__ float ld1(const void* p, int off) {
  return BF16 ? bf2f(((const unsigned short*)p)[off]) : ((const float*)p)[off];
}

// load 16 contiguous elements, widened to fp32
template <bool BF16>
__device__ __forceinline__ void ld16(const void* p, int elem_off, float* dst) {
  if (BF16) {
    const u16x8* wp = (const u16x8*)((const unsigned short*)p + elem_off);
#pragma unroll
    for (int m = 0; m < 2; ++m) {
      u16x8 v = wp[m];
#pragma unroll
      for (int e = 0; e < 8; ++e) dst[m * 8 + e] = bf2f(v[e]);
    }
  } else {
    const float4* wp = (const float4*)((const float*)p + elem_off);
#pragma unroll
    for (int m = 0; m < 4; ++m) {
      float4 v = wp[m];
      dst[m * 4 + 0] = v.x; dst[m * 4 + 1] = v.y;
      dst[m * 4 + 2] = v.z; dst[m * 4 + 3] = v.w;
    }
  }
}

// 16-MAC dot of register weights against 16 LDS floats (4x ds_read_b128)
__device__ __forceinline__ float dot16(const float* w, const float4* y,
                                       float init) {
  float a0 = init, a1 = 0.0f;
#pragma unroll
  for (int q = 0; q < 4; ++q) {
    const float4 v = y[q];
    a0 = fmaf(w[4 * q + 0], v.x, a0);
    a1 = fmaf(w[4 * q + 1], v.y, a1);
    a0 = fmaf(w[4 * q + 2], v.z, a0);
    a1 = fmaf(w[4 * q + 3], v.w, a1);
  }
  return a0 + a1;
}

// 8-layer RNN stack, superstep-pipelined (k=4): wave = layer l; at superstep
// s, wave l computes t in [4(s-l), 4(s-l)+4). Cross-wave handoff via ybuf
// (double-buffered by superstep parity) + ONE barrier per superstep. The
// tanh recurrence stays within the wave: per substep, split-K halves combine
// via shfl_xor, then a within-wave LDS exchange (hxch) rebuilds the
// distributed h. The exchange is fenced with s_waitcnt lgkmcnt(0) +
// sched_barrier: write completes before the read issues (no reliance on
// same-wave DS ordering). ih-partials hoisted (h-independent).
// fc dot: wave w<4 handles sub-timestep i=w of the previous superstep's
// top-layer outputs -> mid[] (LDS). No global memory ops in the loop.
// NOTE: seq and mid may ALIAS (stack 2) — no __restrict__ on them.
template <bool BF16>
__device__ __forceinline__ void run_stack(
    int tid, int l, int j, int kh, int koff,
    const void* __restrict__ Wih0, const void* __restrict__ Wih,
    const void* __restrict__ Whh,  const void* __restrict__ bih,
    const void* __restrict__ bhh,  const void* __restrict__ fcW,
    const void* __restrict__ fcb,
    const float* seq, float* mid,
    float (&ybuf)[2][NL][KSUP][HDIM],
    float (&hxch)[NL][HDIM],
    float (&hvec)[16], float& hown)
{
  float whh[16], wih[16], fcd[16];
  float w0 = 0.0f, bias = 0.0f, fcbias = 0.0f;
  ld16<BF16>(Whh, (l * HDIM + j) * HDIM + koff, whh);
  if (l > 0) {
    ld16<BF16>(Wih, ((l - 1) * HDIM + j) * HDIM + koff, wih);
  } else {
#pragma unroll
    for (int i = 0; i < 16; ++i) wih[i] = 0.0f;
    if (kh == 0) w0 = ld1<BF16>(Wih0, j);
  }
  if (l < 4) {
    ld16<BF16>(fcW, koff, fcd);
    fcbias = ld1<BF16>(fcb, 0);
  }
  if (kh == 0)
    bias = ld1<BF16>(bih, l * HDIM + j) + ld1<BF16>(bhh, l * HDIM + j);

#pragma unroll 2
  for (int s = 0; s < NST; ++s) {
    const int rb = (s & 1) ^ 1;   // read: written by others at superstep s-1
    const int wb = s & 1;         // write: read by others at superstep s+1
    // ---- fc dot (waves 0-3, one sub-timestep each) ----
    if (l < 4) {
      const unsigned sf = (unsigned)(s - NL);
      if (sf < (unsigned)NSUP) {
        float f = dot16(fcd, (const float4*)&ybuf[rb][NL - 1][l][koff], 0.0f);
        f += __shfl_xor(f, 32, 64);
        if ((tid & 63) == 0) mid[((int)sf << 2) + l] = f + fcbias;
      }
    }
    // ---- own layer's 4 timesteps ----
    const unsigned sa = (unsigned)(s - l);
    if (sa < (unsigned)NSUP) {
      const int t0 = (int)sa << 2;
      float e[KSUP];                     // h-independent ih partials
      if (l == 0) {
#pragma unroll
        for (int i = 0; i < KSUP; ++i) e[i] = fmaf(w0, seq[t0 + i], bias);
      } else {
#pragma unroll
        for (int i = 0; i < KSUP; ++i)
          e[i] = dot16(wih, (const float4*)&ybuf[rb][l - 1][i][koff], bias);
      }
#pragma unroll
      for (int i = 0; i < KSUP; ++i) {
        float a0 = e[i], a1 = 0.0f;
#pragma unroll
        for (int q = 0; q < 8; ++q) {
          a0 = fmaf(whh[2 * q + 0], hvec[2 * q + 0], a0);
          a1 = fmaf(whh[2 * q + 1], hvec[2 * q + 1], a1);
        }
        float p = a0 + a1;
        p += __shfl_xor(p, 32, 64);      // combine k-halves
        const float h = fast_tanh(p);
        hown = h;
        if (kh == 0) {
          hxch[l][j] = h;                // within-wave exchange
          ybuf[wb][l][i][j] = h;         // cross-wave handoff (next superstep)
        }
        // Fence: ds_write must complete before the read-back issues; the
        // "memory" clobber + sched_barrier also pin compiler ordering.
        asm volatile("s_waitcnt lgkmcnt(0)" ::: "memory");
        __builtin_amdgcn_sched_barrier(0);
        const float4* hx = (const float4*)&hxch[l][koff];
        const float4 H0 = hx[0], H1 = hx[1], H2 = hx[2], H3 = hx[3];
        hvec[0]  = H0.x; hvec[1]  = H0.y; hvec[2]  = H0.z; hvec[3]  = H0.w;
        hvec[4]  = H1.x; hvec[5]  = H1.y; hvec[6]  = H1.z; hvec[7]  = H1.w;
        hvec[8]  = H2.x; hvec[9]  = H2.y; hvec[10] = H2.z; hvec[11] = H2.w;
        hvec[12] = H3.x; hvec[13] = H3.y; hvec[14] = H3.z; hvec[15] = H3.w;
      }
    }
    __syncthreads();                     // one barrier per 4 timesteps
  }
}

// Dtype probe: bf16-packed N(0,1) concentrates the low-half exponent field
// in [112,132]; fp32 low bits are ~uniform mantissa (~8% hit rate).
__global__ void detect_dtype_kernel(const unsigned int* __restrict__ xu,
                                    int* __restrict__ flag) {
  const int tid = threadIdx.x;
  unsigned int lo = xu[tid] & 0xFFFFu;
  int e = (int)((lo >> 7) & 0xFFu);
  int cnt = __syncthreads_count((e >= 112 && e <= 132) ? 1 : 0);
  if (tid == 0) *flag = (cnt > 128) ? 1 : 0;
}

template <bool BF16>
__global__ __launch_bounds__(NTHR) void radar_rnn_kernel(
    const int* __restrict__ flag,
    const void* __restrict__ x,
    const void* __restrict__ h0,
    const void* __restrict__ W1ih0, const void* __restrict__ W1ih,
    const void* __restrict__ W1hh,  const void* __restrict__ b1ih,
    const void* __restrict__ b1hh,  const void* __restrict__ fc1W,
    const void* __restrict__ fc1b,
    const void* __restrict__ W2ih0, const void* __restrict__ W2ih,
    const void* __restrict__ W2hh,  const void* __restrict__ b2ih,
    const void* __restrict__ b2hh,  const void* __restrict__ outW,
    const void* __restrict__ outb,
    void* __restrict__ out)
{
  if (*flag != (BF16 ? 1 : 0)) return;

  __shared__ __align__(16) float seq[TLEN];     // stack-1 input scalars
  __shared__ __align__(16) float midbuf[TLEN];  // fc1 out = stack-2 in = y
  __shared__ __align__(16) float ybuf[2][NL][KSUP][HDIM];
  __shared__ __align__(16) float hxch[NL][HDIM];

  const int tid = threadIdx.x;
  const int b = blockIdx.x;
  const int l = tid >> 6;          // wave = layer
  const int lane = tid & 63;
  const int j = lane & 31;         // output row
  const int kh = lane >> 5;        // k-half (split-K 2)
  const int koff = kh << 4;

  // stage x[b,:] into LDS as fp32
  if (BF16) {
    const u16x8* xv = (const u16x8*)((const unsigned short*)x + (size_t)b * TLEN);
    for (int i = tid; i < TLEN / 8; i += NTHR) {
      u16x8 v = xv[i];
#pragma unroll
      for (int e = 0; e < 8; ++e) seq[i * 8 + e] = bf2f(v[e]);
    }
  } else {
    const float4* xv = (const float4*)((const float*)x + (size_t)b * TLEN);
    for (int i = tid; i < TLEN / 4; i += NTHR) {
      float4 v = xv[i];
      seq[i * 4 + 0] = v.x; seq[i * 4 + 1] = v.y;
      seq[i * 4 + 2] = v.z; seq[i * 4 + 3] = v.w;
    }
  }

  // distributed initial hidden state: lane (j,kh) holds h0[l,b,koff..koff+16)
  float hvec[16];
  float hown = 0.0f;
  ld16<BF16>(h0, (l * NBATCH + b) * HDIM + koff, hvec);
  __syncthreads();

  // stack 1: seq -> fc1 results in midbuf; hvec/hown end as h1 state
  run_stack<BF16>(tid, l, j, kh, koff, W1ih0, W1ih, W1hh, b1ih, b1hh,
                  fc1W, fc1b, seq, midbuf, ybuf, hxch, hvec, hown);
  // stack 2: midbuf as input (h1 carried in hvec); y overwrites consumed
  // midbuf slots (write trails read by 8 supersteps = 32 timesteps)
  run_stack<BF16>(tid, l, j, kh, koff, W2ih0, W2ih, W2hh, b2ih, b2hh,
                  outW, outb, midbuf, midbuf, ybuf, hxch, hvec, hown);

  // flush y (midbuf) to global, coalesced (loop ended with a barrier)
  if (BF16) {
    __hip_bfloat16* o = (__hip_bfloat16*)out + (size_t)b * TLEN;
    for (int i = tid; i < TLEN; i += NTHR) o[i] = __float2bfloat16(midbuf[i]);
  } else {
    float* o = (float*)out + (size_t)b * TLEN;
    for (int i = tid; i < TLEN; i += NTHR) o[i] = midbuf[i];
  }
  // final hidden states h2: [L, B, H]
  if (!kh) {
    const size_t hidx =
        (size_t)NBATCH * TLEN + (size_t)(l * NBATCH + b) * HDIM + j;
    if (BF16)
      ((__hip_bfloat16*)out)[hidx] = __float2bfloat16(hown);
    else
      ((float*)out)[hidx] = hown;
  }
}

extern "C" void kernel_launch(void* const* d_in, const int* in_sizes, int n_in,
                              void* d_out, int out_size, void* d_ws, size_t ws_size,
                              hipStream_t stream) {
  int* flag = (int*)d_ws;
  detect_dtype_kernel<<<dim3(1), dim3(256), 0, stream>>>(
      (const unsigned int*)d_in[0], flag);

  radar_rnn_kernel<true><<<dim3(NBATCH), dim3(NTHR), 0, stream>>>(
      flag, d_in[0], d_in[1], d_in[2], d_in[3], d_in[4], d_in[5], d_in[6],
      d_in[7], d_in[8], d_in[9], d_in[10], d_in[11], d_in[12], d_in[13],
      d_in[14], d_in[15], d_out);
  radar_rnn_kernel<false><<<dim3(NBATCH), dim3(NTHR), 0, stream>>>(
      flag, d_in[0], d_in[1], d_in[2], d_in[3], d_in[4], d_in[5], d_in[6],
      d_in[7], d_in[8], d_in[9], d_in[10], d_in[11], d_in[12], d_in[13],
      d_in[14], d_in[15], d_out);
}